// Round 18
// baseline (281.424 us; speedup 1.0000x reference)
//
#include <hip/hip_runtime.h>
#include <hip/hip_bf16.h>

typedef unsigned short u16;
typedef unsigned int u32;
typedef unsigned char u8;
using short8 = __attribute__((ext_vector_type(8))) short;
using short4v = __attribute__((ext_vector_type(4))) short;
using f32x4  = __attribute__((ext_vector_type(4))) float;
using float4v = __attribute__((ext_vector_type(4))) float;
using u32x2  = __attribute__((ext_vector_type(2))) unsigned int;

__device__ __forceinline__ u16 f2bf(float f) {
    __hip_bfloat16 h = __float2bfloat16(f);
    union { __hip_bfloat16 h; u16 u; } cv; cv.h = h; return cv.u;
}
__device__ __forceinline__ float bf2f(u16 u) {
    union { u32 u; float f; } cv; cv.u = ((u32)u) << 16; return cv.f;
}
__device__ __forceinline__ u32 fbits(float f) {
    union { float f; u32 u; } cv; cv.f = f; return cv.u;
}

__device__ __forceinline__ void gload_lds16(const void* g, void* l) {
    __builtin_amdgcn_global_load_lds(
        (const __attribute__((address_space(1))) u32*)g,
        (__attribute__((address_space(3))) u32*)l, 16, 0, 0);
}

// bijective XCD-chunk remap (m204)
__device__ __forceinline__ int xcd_remap(int flat, int nwg) {
    int q = nwg >> 3, r = nwg & 7;
    int xcd = flat & 7, pos = flat >> 3;
    int start = xcd < r ? xcd * (q + 1) : r * (q + 1) + (xcd - r) * q;
    return start + pos;
}

// ---- prep: fused {4x weight transpose fp32->bf16} + {LayerNorm1} ----
__global__ __launch_bounds__(256) void prep_kernel(const float* __restrict__ Wq,
                                                   const float* __restrict__ Wo,
                                                   const float* __restrict__ Wf1,
                                                   const float* __restrict__ Wf2,
                                                   u16* __restrict__ Tq,
                                                   u16* __restrict__ To,
                                                   u16* __restrict__ Tf1,
                                                   u16* __restrict__ Tf2,
                                                   const float* __restrict__ x,
                                                   const float* __restrict__ gain,
                                                   const float* __restrict__ beta,
                                                   u16* __restrict__ h1) {
    __shared__ float tile[32][33];
    __shared__ float ws[8];
    int id = blockIdx.x;
    if (id < 6912) {
        const float* W; u16* Wt; int K, N, local;
        if (id < 1728)      { W = Wq;  Wt = Tq;  K = 768;  N = 2304; local = id; }
        else if (id < 2304) { W = Wo;  Wt = To;  K = 768;  N = 768;  local = id - 1728; }
        else if (id < 4608) { W = Wf1; Wt = Tf1; K = 768;  N = 3072; local = id - 2304; }
        else                { W = Wf2; Wt = Tf2; K = 3072; N = 768;  local = id - 4608; }
        int bx = N >> 5;
        int n0 = (local % bx) * 32, k0 = (local / bx) * 32;
        int tx = threadIdx.x & 31, ty = threadIdx.x >> 5;
        for (int i = 0; i < 4; i++) {
            int k = ty + i * 8;
            tile[k][tx] = W[(long)(k0 + k) * N + n0 + tx];
        }
        __syncthreads();
        for (int i = 0; i < 4; i++) {
            int n = ty + i * 8;
            Wt[(long)(n0 + n) * K + k0 + tx] = f2bf(tile[tx][n]);
        }
    } else {
        int row = id - 6912;
        const float* xr = x + (long)row * 768;
        int tid = threadIdx.x;
        float v[3];
        float s = 0.f, s2 = 0.f;
        for (int j = 0; j < 3; j++) {
            v[j] = xr[tid + 256 * j];
            s += v[j]; s2 += v[j] * v[j];
        }
        for (int off = 32; off; off >>= 1) {
            s  += __shfl_down(s, off);
            s2 += __shfl_down(s2, off);
        }
        int lane = tid & 63, w = tid >> 6;
        if (lane == 0) { ws[w] = s; ws[4 + w] = s2; }
        __syncthreads();
        s  = ws[0] + ws[1] + ws[2] + ws[3];
        s2 = ws[4] + ws[5] + ws[6] + ws[7];
        float mu  = s * (1.f / 768.f);
        float var = s2 * (1.f / 768.f) - mu * mu;
        float rs  = rsqrtf(var + 1e-5f);
        for (int j = 0; j < 3; j++) {
            int c = tid + 256 * j;
            h1[(long)row * 768 + c] = f2bf((v[j] - mu) * rs * gain[c] + beta[c]);
        }
    }
}

// ---------------- V transpose: qkv[B][S][2304] (V slice) -> Vt[B*H][64][2048] ------------
__global__ __launch_bounds__(256) void transpose_v(const u16* __restrict__ qkv,
                                                   u16* __restrict__ Vt) {
    __shared__ u16 tile[64][72];
    int s0 = blockIdx.x * 64;
    int bh = blockIdx.y;
    int b = bh / 12, h = bh % 12;
    int tid = threadIdx.x;
    const u16* src = qkv + (long)b * 2048 * 2304 + 1536 + h * 64;
    #pragma unroll
    for (int j = 0; j < 2; ++j) {
        int c = tid + j * 256;
        int srow = c >> 3, ch = c & 7;
        *(short8*)&tile[srow][ch * 8] = *(const short8*)(src + (long)(s0 + srow) * 2304 + ch * 8);
    }
    __syncthreads();
    u16* dst = Vt + (long)bh * 64 * 2048 + s0;
    #pragma unroll
    for (int j = 0; j < 2; ++j) {
        int c = tid + j * 256;
        int d = c >> 3, ch = c & 7;
        short8 v;
        #pragma unroll
        for (int e = 0; e < 8; ++e) v[e] = (short)tile[ch * 8 + e][d];
        *(short8*)(dst + (long)d * 2048 + ch * 8) = v;
    }
}

// ---------------- LayerNorm fp32 -> bf16 (standalone, for ln2) ----------------
__global__ __launch_bounds__(256) void ln_kernel(const float* __restrict__ x,
                                                 const float* __restrict__ gain,
                                                 const float* __restrict__ beta,
                                                 u16* __restrict__ out) {
    int row = blockIdx.x;
    const float* xr = x + (long)row * 768;
    int tid = threadIdx.x;
    float v[3];
    float s = 0.f, s2 = 0.f;
    for (int j = 0; j < 3; j++) {
        v[j] = xr[tid + 256 * j];
        s += v[j]; s2 += v[j] * v[j];
    }
    for (int off = 32; off; off >>= 1) {
        s  += __shfl_down(s, off);
        s2 += __shfl_down(s2, off);
    }
    __shared__ float ws[8];
    int lane = tid & 63, w = tid >> 6;
    if (lane == 0) { ws[w] = s; ws[4 + w] = s2; }
    __syncthreads();
    s  = ws[0] + ws[1] + ws[2] + ws[3];
    s2 = ws[4] + ws[5] + ws[6] + ws[7];
    float mu  = s * (1.f / 768.f);
    float var = s2 * (1.f / 768.f) - mu * mu;
    float rs  = rsqrtf(var + 1e-5f);
    for (int j = 0; j < 3; j++) {
        int c = tid + 256 * j;
        out[(long)row * 768 + c] = f2bf((v[j] - mu) * rs * gain[c] + beta[c]);
    }
}

// -- bf16 GEMM v6: 128xNT tile (NT=128/256), BK=32, 3-buffer ring, depth-2 counted vmcnt --
// EPI 0: bias->bf16; 1: bias+residual->fp32; 2: bias+gelu->bf16; 3: raw bf16 partial.
template <int EPI, int NT>
__global__ __launch_bounds__(256) void gemm_bf16(const u16* __restrict__ A, int lda,
                                                 const u16* __restrict__ Bt, int ldb,
                                                 const float* __restrict__ bias,
                                                 const float* __restrict__ res,
                                                 void* __restrict__ Cout0,
                                                 void* __restrict__ Cout1,
                                                 void* __restrict__ Cout2,
                                                 void* __restrict__ Cout3,
                                                 int M, int N, int K, int nN) {
    constexpr int NFRAG = NT / 32;      // B fragments per wave (per K-chunk)
    constexpr int BPASS = NT / 64;      // staging passes for B
    __shared__ alignas(16) u16 As[3][128 * 32];
    __shared__ alignas(16) u16 Bs[3][NT * 32];
    int nwg = gridDim.x;
    int wgid = xcd_remap(blockIdx.x, nwg);
    int tN = (wgid % nN) * NT, tM = (wgid / nN) * 128;
    int z = blockIdx.z;
    const u16* Ab = A + (long)z * K;
    const u16* Bb = Bt + (long)z * K;
    void* Cw = (z == 0) ? Cout0 : (z == 1) ? Cout1 : (z == 2) ? Cout2 : Cout3;
    int tid = threadIdx.x;
    int wid = tid >> 6, lane = tid & 63;
    int wm = wid >> 1, wn = wid & 1;
    int g = lane >> 4, r = lane & 15;
    int srow = tid >> 2;
    int scol = tid & 3;

    f32x4 acc[4][NFRAG] = {};
    int KT = K >> 5;

    auto stage = [&](int kt, int buf) {
        int k0 = kt << 5;
        u16* ab = As[buf];
        u16* bb = Bs[buf];
        #pragma unroll
        for (int j = 0; j < 2; ++j) {
            int row = j * 64 + srow;
            int slot = scol ^ (row & 3);
            gload_lds16(Ab + (long)(tM + row) * lda + k0 + slot * 8, ab + (j * 64 + wid * 16) * 32);
        }
        #pragma unroll
        for (int j = 0; j < BPASS; ++j) {
            int row = j * 64 + srow;
            int slot = scol ^ (row & 3);
            gload_lds16(Bb + (long)(tN + row) * ldb + k0 + slot * 8, bb + (j * 64 + wid * 16) * 32);
        }
    };

    stage(0, 0);
    stage(1, 1);
    int sb = 2, cb = 0;
    for (int kt = 0; kt < KT; ++kt) {
        if (kt + 2 < KT) {
            stage(kt + 2, sb);
            if (++sb == 3) sb = 0;
            if constexpr (NT == 256)
                asm volatile("s_waitcnt vmcnt(12)" ::: "memory");
            else
                asm volatile("s_waitcnt vmcnt(8)" ::: "memory");
        } else if (kt + 1 < KT) {
            if constexpr (NT == 256)
                asm volatile("s_waitcnt vmcnt(6)" ::: "memory");
            else
                asm volatile("s_waitcnt vmcnt(4)" ::: "memory");
        } else {
            asm volatile("s_waitcnt vmcnt(0)" ::: "memory");
        }
        __builtin_amdgcn_sched_barrier(0);
        __builtin_amdgcn_s_barrier();
        const u16* ab = As[cb];
        const u16* bb = Bs[cb];
        if (++cb == 3) cb = 0;

        short8 af[4], bf[NFRAG];
        #pragma unroll
        for (int mi = 0; mi < 4; ++mi) {
            int row = wm * 64 + mi * 16 + r;
            af[mi] = *(const short8*)(ab + row * 32 + ((g ^ (row & 3)) * 8));
        }
        #pragma unroll
        for (int ni = 0; ni < NFRAG; ++ni) {
            int row = wn * (NT / 2) + ni * 16 + r;
            bf[ni] = *(const short8*)(bb + row * 32 + ((g ^ (row & 3)) * 8));
        }
        #pragma unroll
        for (int mi = 0; mi < 4; ++mi)
            #pragma unroll
            for (int ni = 0; ni < NFRAG; ++ni)
                acc[mi][ni] = __builtin_amdgcn_mfma_f32_16x16x32_bf16(af[mi], bf[ni], acc[mi][ni], 0, 0, 0);
        __builtin_amdgcn_s_barrier();
    }

    #pragma unroll
    for (int mi = 0; mi < 4; mi++) {
        #pragma unroll
        for (int ni = 0; ni < NFRAG; ni++) {
            int col = tN + wn * (NT / 2) + ni * 16 + r;
            float bv = (EPI == 3) ? 0.f : bias[col];
            #pragma unroll
            for (int reg = 0; reg < 4; reg++) {
                int row = tM + wm * 64 + mi * 16 + g * 4 + reg;
                float v = acc[mi][ni][reg] + bv;
                if (EPI == 1) {
                    v += res[(long)row * N + col];
                    ((float*)Cw)[(long)row * N + col] = v;
                } else if (EPI == 2) {
                    v = 0.5f * v * (1.f + erff(v * 0.70710678118f));
                    ((u16*)Cw)[(long)row * N + col] = f2bf(v);
                } else {
                    ((u16*)Cw)[(long)row * N + col] = f2bf(v);
                }
            }
        }
    }
}

// ------- fc2 4-way split-K combine: out = P0+P1+P2+P3 + bias + res (partials bf16) ------
__global__ __launch_bounds__(192) void fc2_combine4(const u16* __restrict__ P0,
                                                    const u16* __restrict__ P1,
                                                    const u16* __restrict__ P2,
                                                    const u16* __restrict__ P3,
                                                    const float* __restrict__ bias,
                                                    const float* __restrict__ res,
                                                    float* __restrict__ out) {
    long row = blockIdx.x;
    int c = threadIdx.x * 4;
    long i = row * 768 + c;
    short4v a = *(const short4v*)(P0 + i);
    short4v b = *(const short4v*)(P1 + i);
    short4v d = *(const short4v*)(P2 + i);
    short4v e = *(const short4v*)(P3 + i);
    float4v bs = *(const float4v*)(bias + c);
    float4v rr = *(const float4v*)(res + i);
    float4v o;
    #pragma unroll
    for (int j = 0; j < 4; ++j)
        o[j] = (bf2f((u16)a[j]) + bf2f((u16)b[j])) + (bf2f((u16)d[j]) + bf2f((u16)e[j])) + bs[j] + rr[j];
    *(float4v*)(out + i) = o;
}

// ----- split-K flash attention (causal), swapped-QK^T + packed-P, chunk=512 -----
__device__ __constant__ u8 SLOT_QI[40] = {
    15,15,15,15, 14,14,14, 13,13,13, 12,12,12, 11,11,11, 10,10, 9,9, 8,8, 7,7, 6, 5, 4, 3,
    14,10,6,2,  13,9,5,1,  12,8,4,0 };
__device__ __constant__ u8 SLOT_C[40] = {
    0,1,2,3, 0,1,2, 0,1,2, 0,1,2, 0,1,2, 0,1, 0,1, 0,1, 0,1, 0, 0, 0, 0,
    3,2,1,0, 3,2,1,0, 3,2,1,0 };

__global__ __launch_bounds__(256) void attn_kernel(const u16* __restrict__ qkv,
                                                   const u16* __restrict__ Vt,
                                                   u16* __restrict__ Opart,
                                                   float* __restrict__ Ml) {
    __shared__ alignas(16) u16 Ks[2 * 64 * 64];
    __shared__ alignas(16) u16 Vs[2 * 64 * 64];
    __shared__ alignas(16) u16 Ps[4 * 16 * 64];
    int flat = blockIdx.x;
    int s = flat / 24, bh = flat % 24;
    int qi = SLOT_QI[s], c = SLOT_C[s];
    int b = bh / 12, h = bh % 12;
    int tid = threadIdx.x;
    int w = tid >> 6, lane = tid & 63;
    int g = lane >> 4, r = lane & 15;
    int qt0 = qi * 128;
    int qw0 = qt0 + w * 32;
    int kvbase = c * 512;
    int nit = (c < (qi >> 2)) ? 8 : (2 * (qi & 3) + 2);
    const u16* base = qkv + (long)b * 2048 * 2304;
    const u16* Qb = base + h * 64;
    const u16* Kb = base + 768 + h * 64;
    const u16* Vtb = Vt + (long)bh * 64 * 2048;

    const float SC = 0.125f * 1.44269504f;
    short8 qf[2][2];
    #pragma unroll
    for (int fi = 0; fi < 2; ++fi) {
        const u16* qrow = Qb + (long)(qw0 + fi * 16 + r) * 2304;
        qf[fi][0] = *(const short8*)(qrow + 8 * g);
        qf[fi][1] = *(const short8*)(qrow + 32 + 8 * g);
        #pragma unroll
        for (int kh = 0; kh < 2; ++kh)
            #pragma unroll
            for (int j = 0; j < 8; ++j)
                qf[fi][kh][j] = (short)f2bf(bf2f((u16)qf[fi][kh][j]) * SC);
    }

    f32x4 oacc[2][4] = {};
    float mrow[2] = {8.0f, 8.0f};
    float ps0[2] = {0.f, 0.f}, ps1[2] = {0.f, 0.f};

    auto stage = [&](int kt) {
        int kv0 = kvbase + kt * 64;
        u16* kb = Ks + (kt & 1) * 4096;
        u16* vb = Vs + (kt & 1) * 4096;
        #pragma unroll
        for (int j = 0; j < 2; ++j) {
            int cc = w * 128 + j * 64 + lane;
            int row = cc >> 3;
            int slot = (cc & 7) ^ (row & 7);
            gload_lds16(Kb + (long)(kv0 + row) * 2304 + slot * 8, kb + (w * 128 + j * 64) * 8);
            gload_lds16(Vtb + (long)row * 2048 + kv0 + slot * 8, vb + (w * 128 + j * 64) * 8);
        }
    };

    stage(0);
    for (int kt = 0; kt < nit; ++kt) {
        int kv0 = kvbase + kt * 64;
        if (kt + 1 < nit) {
            stage(kt + 1);
            asm volatile("s_waitcnt vmcnt(4)" ::: "memory");
        } else {
            asm volatile("s_waitcnt vmcnt(0)" ::: "memory");
        }
        __builtin_amdgcn_sched_barrier(0);
        __builtin_amdgcn_s_barrier();
        const u16* kb = Ks + (kt & 1) * 4096;
        const u16* vb = Vs + (kt & 1) * 4096;

        bool act0 = kv0 <= qw0 + 15;
        bool act1 = kv0 <= qw0 + 31;

        if (act1) {
            f32x4 sc[2][4] = {};
            __builtin_amdgcn_s_setprio(1);
            #pragma unroll
            for (int nt = 0; nt < 4; ++nt)
                #pragma unroll
                for (int kh = 0; kh < 2; ++kh) {
                    short8 bk = *(const short8*)(kb + (nt * 16 + r) * 64 + ((kh * 32 + g * 8) ^ ((r & 7) << 3)));
                    sc[1][nt] = __builtin_amdgcn_mfma_f32_16x16x32_bf16(bk, qf[1][kh], sc[1][nt], 0, 0, 0);
                    if (act0)
                        sc[0][nt] = __builtin_amdgcn_mfma_f32_16x16x32_bf16(bk, qf[0][kh], sc[0][nt], 0, 0, 0);
                }
            __builtin_amdgcn_s_setprio(0);

            #pragma unroll
            for (int fi = 0; fi < 2; ++fi) {
                if (fi == 0 && !act0) continue;
                if ((kv0 + 63) > (qw0 + fi * 16)) {
                    int q = qw0 + fi * 16 + r;
                    #pragma unroll
                    for (int nt = 0; nt < 4; ++nt)
                        #pragma unroll
                        for (int reg = 0; reg < 4; ++reg)
                            if ((kv0 + nt * 16 + g * 4 + reg) > q)
                                sc[fi][nt][reg] = -1e30f;
                }
            }

            float tl[2];
            bool need = false;
            #pragma unroll
            for (int fi = 0; fi < 2; ++fi) {
                if (fi == 0 && !act0) continue;
                float m0 = fmaxf(fmaxf(sc[fi][0][0], sc[fi][0][1]), fmaxf(sc[fi][0][2], sc[fi][0][3]));
                float m1 = fmaxf(fmaxf(sc[fi][1][0], sc[fi][1][1]), fmaxf(sc[fi][1][2], sc[fi][1][3]));
                float m2 = fmaxf(fmaxf(sc[fi][2][0], sc[fi][2][1]), fmaxf(sc[fi][2][2], sc[fi][2][3]));
                float m3 = fmaxf(fmaxf(sc[fi][3][0], sc[fi][3][1]), fmaxf(sc[fi][3][2], sc[fi][3][3]));
                tl[fi] = fmaxf(fmaxf(m0, m1), fmaxf(m2, m3));
                need = need || (tl[fi] > mrow[fi] + 8.f);
            }
            if (__any(need)) {
                #pragma unroll
                for (int fi = 0; fi < 2; ++fi) {
                    if (fi == 0 && !act0) continue;
                    float rm = tl[fi];
                    rm = fmaxf(rm, __shfl_xor(rm, 16));
                    rm = fmaxf(rm, __shfl_xor(rm, 32));
                    float mnew = fmaxf(mrow[fi], rm);
                    float alpha = exp2f(mrow[fi] - mnew);
                    mrow[fi] = mnew;
                    ps0[fi] *= alpha; ps1[fi] *= alpha;
                    #pragma unroll
                    for (int reg = 0; reg < 4; ++reg) {
                        float ar = __shfl(alpha, (lane & 48) | (g * 4 + reg));
                        #pragma unroll
                        for (int dt = 0; dt < 4; ++dt) oacc[fi][dt][reg] *= ar;
                    }
                }
            }

            u16* Pr = Ps + (w * 16 + r) * 64;
            short8 pf[2][2];
            #pragma unroll
            for (int fi = 0; fi < 2; ++fi) {
                if (fi == 0 && !act0) continue;
                #pragma unroll
                for (int nt = 0; nt < 4; ++nt) {
                    float p0 = exp2f(sc[fi][nt][0] - mrow[fi]);
                    float p1 = exp2f(sc[fi][nt][1] - mrow[fi]);
                    float p2 = exp2f(sc[fi][nt][2] - mrow[fi]);
                    float p3 = exp2f(sc[fi][nt][3] - mrow[fi]);
                    ps0[fi] += p0 + p2;
                    ps1[fi] += p1 + p3;
                    u32 lo = __builtin_amdgcn_perm(fbits(p1), fbits(p0), 0x07060302);
                    u32 hi = __builtin_amdgcn_perm(fbits(p3), fbits(p2), 0x07060302);
                    int col = (nt * 16 + g * 4) ^ ((r & 7) << 3);
                    *(u32x2*)(Pr + col) = u32x2{lo, hi};
                }
                pf[fi][0] = *(const short8*)(Pr + ((g * 8) ^ ((r & 7) << 3)));
                pf[fi][1] = *(const short8*)(Pr + ((32 + g * 8) ^ ((r & 7) << 3)));
            }

            __builtin_amdgcn_s_setprio(1);
            #pragma unroll
            for (int dt = 0; dt < 4; ++dt)
                #pragma unroll
                for (int kc = 0; kc < 2; ++kc) {
                    short8 vf = *(const short8*)(vb + (dt * 16 + r) * 64 + ((kc * 32 + g * 8) ^ ((r & 7) << 3)));
                    oacc[1][dt] = __builtin_amdgcn_mfma_f32_16x16x32_bf16(pf[1][kc], vf, oacc[1][dt], 0, 0, 0);
                    if (act0)
                        oacc[0][dt] = __builtin_amdgcn_mfma_f32_16x16x32_bf16(pf[0][kc], vf, oacc[0][dt], 0, 0, 0);
                }
            __builtin_amdgcn_s_setprio(0);
        }
        __builtin_amdgcn_s_barrier();
    }

    float lrow[2];
    #pragma unroll
    for (int fi = 0; fi < 2; ++fi) {
        float l = ps0[fi] + ps1[fi];
        l += __shfl_xor(l, 16);
        l += __shfl_xor(l, 32);
        lrow[fi] = l;
    }

    long pbase = ((long)c * 24 + bh) * 2048;
    #pragma unroll
    for (int fi = 0; fi < 2; ++fi)
        #pragma unroll
        for (int dt = 0; dt < 4; ++dt)
            #pragma unroll
            for (int reg = 0; reg < 4; ++reg) {
                int q = qw0 + fi * 16 + g * 4 + reg;
                int d = dt * 16 + r;
                Opart[(pbase + q) * 64 + d] = f2bf(oacc[fi][dt][reg]);
            }
    if ((lane & 48) == 0) {
        #pragma unroll
        for (int fi = 0; fi < 2; ++fi) {
            int q = qw0 + fi * 16 + r;
            Ml[(pbase + q) * 2]     = mrow[fi];
            Ml[(pbase + q) * 2 + 1] = lrow[fi];
        }
    }
}

// ---------------- combine split-K partials -> Ob bf16 [B*S][768] (d-pair vectorized) ------
__global__ __launch_bounds__(256) void attn_combine(const u16* __restrict__ Opart,
                                                    const float* __restrict__ Ml,
                                                    u16* __restrict__ Ob) {
    int bh = blockIdx.y;
    int b = bh / 12, h = bh % 12;
    int q = blockIdx.x * 8 + (threadIdx.x >> 5);
    int d = (threadIdx.x & 31) * 2;
    int qi = q >> 7;
    int nact = (qi >> 2) + 1;
    float mv[4], lv[4];
    float M = -1e30f;
    for (int c = 0; c < nact; ++c) {
        long base = ((long)c * 24 + bh) * 2048 + q;
        mv[c] = Ml[base * 2];
        lv[c] = Ml[base * 2 + 1];
        M = fmaxf(M, mv[c]);
    }
    float denom = 0.f, v0 = 0.f, v1 = 0.f;
    for (int c = 0; c < nact; ++c) {
        float wgt = exp2f(mv[c] - M);
        denom += lv[c] * wgt;
        u32 pr = *(const u32*)(Opart + ((((long)c * 24 + bh) * 2048 + q) * 64 + d));
        v0 += wgt * bf2f((u16)(pr & 0xffff));
        v1 += wgt * bf2f((u16)(pr >> 16));
    }
    float inv = 1.0f / denom;
    u32 o = (u32)f2bf(v0 * inv) | ((u32)f2bf(v1 * inv) << 16);
    *(u32*)(Ob + (((long)b * 2048 + q) * 768 + h * 64 + d)) = o;
}

extern "C" void kernel_launch(void* const* d_in, const int* in_sizes, int n_in,
                              void* d_out, int out_size, void* d_ws, size_t ws_size,
                              hipStream_t stream) {
    const float* x     = (const float*)d_in[0];
    const float* ln1_g = (const float*)d_in[1];
    const float* ln1_b = (const float*)d_in[2];
    const float* ln2_g = (const float*)d_in[3];
    const float* ln2_b = (const float*)d_in[4];
    const float* w_qkv = (const float*)d_in[5];
    const float* b_qkv = (const float*)d_in[6];
    const float* w_out = (const float*)d_in[7];
    const float* b_out = (const float*)d_in[8];
    const float* w_fc1 = (const float*)d_in[9];
    const float* b_fc1 = (const float*)d_in[10];
    const float* w_fc2 = (const float*)d_in[11];
    const float* b_fc2 = (const float*)d_in[12];

    char* ws = (char*)d_ws;
    size_t off = 0;
    auto alloc = [&](size_t bytes) { void* p = ws + off; off += (bytes + 255) & ~255ULL; return p; };
    u16* h1    = (u16*)alloc(4096UL * 768 * 2);    // dead after qkv GEMM
    u16* WqkvT = (u16*)alloc(2304UL * 768 * 2);    // dead after qkv GEMM
    u16* WoutT = (u16*)alloc(768UL * 768 * 2);
    u16* Wfc1T = (u16*)alloc(3072UL * 768 * 2);
    u16* Wfc2T = (u16*)alloc(768UL * 3072 * 2);
    u16* qkvb  = (u16*)alloc(4096UL * 2304 * 2);   // dead after attn
    u16* Vtb   = (u16*)alloc(24UL * 64 * 2048 * 2); // dead after attn
    u16* Ob    = (u16*)alloc(4096UL * 768 * 2);     // dead after out-proj
    float* x2  = (float*)alloc(4096UL * 768 * 4);
    // pool shared (time-disjoint): [h2 | gbuf] vs [Opart | Ml]
    char* pool = (char*)alloc(4096UL * 768 * 2 + 4096UL * 3072 * 2);
    u16* h2      = (u16*)pool;
    u16* gbuf    = (u16*)(pool + 4096UL * 768 * 2);
    u16* Opart   = (u16*)pool;
    float* Ml    = (float*)(pool + 4UL * 24 * 2048 * 64 * 2);
    // fc2 split-K (z=4) bf16 partials, aliased over buffers dead by fc2 time:
    u16* P0 = (u16*)qkvb;
    u16* P1 = (u16*)h1;
    u16* P2 = (u16*)Vtb;
    u16* P3 = (u16*)Ob;

    prep_kernel<<<dim3(11008), 256, 0, stream>>>(w_qkv, w_out, w_fc1, w_fc2,
                                                 WqkvT, WoutT, Wfc1T, Wfc2T,
                                                 x, ln1_g, ln1_b, h1);
    gemm_bf16<0, 256><<<dim3(288, 1, 1), 256, 0, stream>>>(h1, 768, WqkvT, 768, b_qkv, nullptr, qkvb, nullptr, nullptr, nullptr, 4096, 2304, 768, 9);
    transpose_v<<<dim3(32, 24), 256, 0, stream>>>(qkvb, Vtb);
    attn_kernel<<<dim3(960), 256, 0, stream>>>(qkvb, Vtb, Opart, Ml);
    attn_combine<<<dim3(256, 24), 256, 0, stream>>>(Opart, Ml, Ob);
    gemm_bf16<1, 128><<<dim3(192, 1, 1), 256, 0, stream>>>(Ob, 768, WoutT, 768, b_out, x, x2, nullptr, nullptr, nullptr, 4096, 768, 768, 6);
    ln_kernel<<<4096, 256, 0, stream>>>(x2, ln2_g, ln2_b, h2);
    gemm_bf16<2, 256><<<dim3(384, 1, 1), 256, 0, stream>>>(h2, 768, Wfc1T, 768, b_fc1, nullptr, gbuf, nullptr, nullptr, nullptr, 4096, 3072, 768, 12);
    gemm_bf16<3, 256><<<dim3(96, 1, 4), 256, 0, stream>>>(gbuf, 3072, Wfc2T, 3072, nullptr, nullptr, P0, P1, P2, P3, 4096, 768, 768, 3);
    fc2_combine4<<<4096, 192, 0, stream>>>(P0, P1, P2, P3, b_fc2, x2, (float*)d_out);
}

// Round 19
// 192.667 us; speedup vs baseline: 1.4607x; 1.4607x over previous
//
#include <hip/hip_runtime.h>
#include <hip/hip_bf16.h>

typedef unsigned short u16;
typedef unsigned int u32;
typedef unsigned char u8;
using short8 = __attribute__((ext_vector_type(8))) short;
using short4v = __attribute__((ext_vector_type(4))) short;
using f32x4  = __attribute__((ext_vector_type(4))) float;
using float4v = __attribute__((ext_vector_type(4))) float;
using u32x2  = __attribute__((ext_vector_type(2))) unsigned int;

__device__ __forceinline__ u16 f2bf(float f) {
    __hip_bfloat16 h = __float2bfloat16(f);
    union { __hip_bfloat16 h; u16 u; } cv; cv.h = h; return cv.u;
}
__device__ __forceinline__ float bf2f(u16 u) {
    union { u32 u; float f; } cv; cv.u = ((u32)u) << 16; return cv.f;
}
__device__ __forceinline__ u32 fbits(float f) {
    union { float f; u32 u; } cv; cv.f = f; return cv.u;
}

__device__ __forceinline__ void gload_lds16(const void* g, void* l) {
    __builtin_amdgcn_global_load_lds(
        (const __attribute__((address_space(1))) u32*)g,
        (__attribute__((address_space(3))) u32*)l, 16, 0, 0);
}

// bijective XCD-chunk remap (m204)
__device__ __forceinline__ int xcd_remap(int flat, int nwg) {
    int q = nwg >> 3, r = nwg & 7;
    int xcd = flat & 7, pos = flat >> 3;
    int start = xcd < r ? xcd * (q + 1) : r * (q + 1) + (xcd - r) * q;
    return start + pos;
}

// ---- prep: fused {4x weight transpose fp32->bf16} + {LayerNorm1} ----
__global__ __launch_bounds__(256) void prep_kernel(const float* __restrict__ Wq,
                                                   const float* __restrict__ Wo,
                                                   const float* __restrict__ Wf1,
                                                   const float* __restrict__ Wf2,
                                                   u16* __restrict__ Tq,
                                                   u16* __restrict__ To,
                                                   u16* __restrict__ Tf1,
                                                   u16* __restrict__ Tf2,
                                                   const float* __restrict__ x,
                                                   const float* __restrict__ gain,
                                                   const float* __restrict__ beta,
                                                   u16* __restrict__ h1) {
    __shared__ float tile[32][33];
    __shared__ float ws[8];
    int id = blockIdx.x;
    if (id < 6912) {
        const float* W; u16* Wt; int K, N, local;
        if (id < 1728)      { W = Wq;  Wt = Tq;  K = 768;  N = 2304; local = id; }
        else if (id < 2304) { W = Wo;  Wt = To;  K = 768;  N = 768;  local = id - 1728; }
        else if (id < 4608) { W = Wf1; Wt = Tf1; K = 768;  N = 3072; local = id - 2304; }
        else                { W = Wf2; Wt = Tf2; K = 3072; N = 768;  local = id - 4608; }
        int bx = N >> 5;
        int n0 = (local % bx) * 32, k0 = (local / bx) * 32;
        int tx = threadIdx.x & 31, ty = threadIdx.x >> 5;
        for (int i = 0; i < 4; i++) {
            int k = ty + i * 8;
            tile[k][tx] = W[(long)(k0 + k) * N + n0 + tx];
        }
        __syncthreads();
        for (int i = 0; i < 4; i++) {
            int n = ty + i * 8;
            Wt[(long)(n0 + n) * K + k0 + tx] = f2bf(tile[tx][n]);
        }
    } else {
        int row = id - 6912;
        const float* xr = x + (long)row * 768;
        int tid = threadIdx.x;
        float v[3];
        float s = 0.f, s2 = 0.f;
        for (int j = 0; j < 3; j++) {
            v[j] = xr[tid + 256 * j];
            s += v[j]; s2 += v[j] * v[j];
        }
        for (int off = 32; off; off >>= 1) {
            s  += __shfl_down(s, off);
            s2 += __shfl_down(s2, off);
        }
        int lane = tid & 63, w = tid >> 6;
        if (lane == 0) { ws[w] = s; ws[4 + w] = s2; }
        __syncthreads();
        s  = ws[0] + ws[1] + ws[2] + ws[3];
        s2 = ws[4] + ws[5] + ws[6] + ws[7];
        float mu  = s * (1.f / 768.f);
        float var = s2 * (1.f / 768.f) - mu * mu;
        float rs  = rsqrtf(var + 1e-5f);
        for (int j = 0; j < 3; j++) {
            int c = tid + 256 * j;
            h1[(long)row * 768 + c] = f2bf((v[j] - mu) * rs * gain[c] + beta[c]);
        }
    }
}

// ---------------- V transpose: qkv[B][S][2304] (V slice) -> Vt[B*H][64][2048] ------------
__global__ __launch_bounds__(256) void transpose_v(const u16* __restrict__ qkv,
                                                   u16* __restrict__ Vt) {
    __shared__ u16 tile[64][72];
    int s0 = blockIdx.x * 64;
    int bh = blockIdx.y;
    int b = bh / 12, h = bh % 12;
    int tid = threadIdx.x;
    const u16* src = qkv + (long)b * 2048 * 2304 + 1536 + h * 64;
    #pragma unroll
    for (int j = 0; j < 2; ++j) {
        int c = tid + j * 256;
        int srow = c >> 3, ch = c & 7;
        *(short8*)&tile[srow][ch * 8] = *(const short8*)(src + (long)(s0 + srow) * 2304 + ch * 8);
    }
    __syncthreads();
    u16* dst = Vt + (long)bh * 64 * 2048 + s0;
    #pragma unroll
    for (int j = 0; j < 2; ++j) {
        int c = tid + j * 256;
        int d = c >> 3, ch = c & 7;
        short8 v;
        #pragma unroll
        for (int e = 0; e < 8; ++e) v[e] = (short)tile[ch * 8 + e][d];
        *(short8*)(dst + (long)d * 2048 + ch * 8) = v;
    }
}

// ---------------- LayerNorm fp32 -> bf16 (standalone, for ln2) ----------------
__global__ __launch_bounds__(256) void ln_kernel(const float* __restrict__ x,
                                                 const float* __restrict__ gain,
                                                 const float* __restrict__ beta,
                                                 u16* __restrict__ out) {
    int row = blockIdx.x;
    const float* xr = x + (long)row * 768;
    int tid = threadIdx.x;
    float v[3];
    float s = 0.f, s2 = 0.f;
    for (int j = 0; j < 3; j++) {
        v[j] = xr[tid + 256 * j];
        s += v[j]; s2 += v[j] * v[j];
    }
    for (int off = 32; off; off >>= 1) {
        s  += __shfl_down(s, off);
        s2 += __shfl_down(s2, off);
    }
    __shared__ float ws[8];
    int lane = tid & 63, w = tid >> 6;
    if (lane == 0) { ws[w] = s; ws[4 + w] = s2; }
    __syncthreads();
    s  = ws[0] + ws[1] + ws[2] + ws[3];
    s2 = ws[4] + ws[5] + ws[6] + ws[7];
    float mu  = s * (1.f / 768.f);
    float var = s2 * (1.f / 768.f) - mu * mu;
    float rs  = rsqrtf(var + 1e-5f);
    for (int j = 0; j < 3; j++) {
        int c = tid + 256 * j;
        out[(long)row * 768 + c] = f2bf((v[j] - mu) * rs * gain[c] + beta[c]);
    }
}

// -- bf16 GEMM v5: 128x128, BK=32, 3-buffer ring, depth-2 prefetch, counted vmcnt(8) -----
// EPI 0: bias->bf16; 1: bias+residual->fp32; 2: bias+gelu->bf16; 3: raw bf16 partial.
template <int EPI>
__global__ __launch_bounds__(256) void gemm_bf16(const u16* __restrict__ A, int lda,
                                                 const u16* __restrict__ Bt, int ldb,
                                                 const float* __restrict__ bias,
                                                 const float* __restrict__ res,
                                                 void* __restrict__ Cout0,
                                                 void* __restrict__ Cout1,
                                                 void* __restrict__ Cout2,
                                                 void* __restrict__ Cout3,
                                                 int M, int N, int K, int nN) {
    __shared__ alignas(16) u16 As[3][128 * 32];
    __shared__ alignas(16) u16 Bs[3][128 * 32];
    int nwg = gridDim.x;
    int wgid = xcd_remap(blockIdx.x, nwg);
    int tN = (wgid % nN) * 128, tM = (wgid / nN) * 128;
    int z = blockIdx.z;
    const u16* Ab = A + (long)z * K;
    const u16* Bb = Bt + (long)z * K;
    void* Cw = (z == 0) ? Cout0 : (z == 1) ? Cout1 : (z == 2) ? Cout2 : Cout3;
    int tid = threadIdx.x;
    int wid = tid >> 6, lane = tid & 63;
    int wm = wid >> 1, wn = wid & 1;
    int g = lane >> 4, r = lane & 15;
    int srow = tid >> 2;
    int scol = tid & 3;

    f32x4 acc[4][4] = {};
    int KT = K >> 5;

    auto stage = [&](int kt, int buf) {
        int k0 = kt << 5;
        u16* ab = As[buf];
        u16* bb = Bs[buf];
        #pragma unroll
        for (int j = 0; j < 2; ++j) {
            int row = j * 64 + srow;
            int slot = scol ^ (row & 3);
            gload_lds16(Ab + (long)(tM + row) * lda + k0 + slot * 8, ab + (j * 64 + wid * 16) * 32);
            gload_lds16(Bb + (long)(tN + row) * ldb + k0 + slot * 8, bb + (j * 64 + wid * 16) * 32);
        }
    };

    stage(0, 0);
    stage(1, 1);
    int sb = 2, cb = 0;
    for (int kt = 0; kt < KT; ++kt) {
        if (kt + 2 < KT) {
            stage(kt + 2, sb);
            if (++sb == 3) sb = 0;
            asm volatile("s_waitcnt vmcnt(8)" ::: "memory");
        } else if (kt + 1 < KT) {
            asm volatile("s_waitcnt vmcnt(4)" ::: "memory");
        } else {
            asm volatile("s_waitcnt vmcnt(0)" ::: "memory");
        }
        __builtin_amdgcn_sched_barrier(0);
        __builtin_amdgcn_s_barrier();
        const u16* ab = As[cb];
        const u16* bb = Bs[cb];
        if (++cb == 3) cb = 0;

        short8 af[4], bf[4];
        #pragma unroll
        for (int mi = 0; mi < 4; ++mi) {
            int row = wm * 64 + mi * 16 + r;
            af[mi] = *(const short8*)(ab + row * 32 + ((g ^ (row & 3)) * 8));
        }
        #pragma unroll
        for (int ni = 0; ni < 4; ++ni) {
            int row = wn * 64 + ni * 16 + r;
            bf[ni] = *(const short8*)(bb + row * 32 + ((g ^ (row & 3)) * 8));
        }
        #pragma unroll
        for (int mi = 0; mi < 4; ++mi)
            #pragma unroll
            for (int ni = 0; ni < 4; ++ni)
                acc[mi][ni] = __builtin_amdgcn_mfma_f32_16x16x32_bf16(af[mi], bf[ni], acc[mi][ni], 0, 0, 0);
        __builtin_amdgcn_s_barrier();
    }

    #pragma unroll
    for (int mi = 0; mi < 4; mi++) {
        #pragma unroll
        for (int ni = 0; ni < 4; ni++) {
            int col = tN + wn * 64 + ni * 16 + r;
            float bv = (EPI == 3) ? 0.f : bias[col];
            #pragma unroll
            for (int reg = 0; reg < 4; reg++) {
                int row = tM + wm * 64 + mi * 16 + g * 4 + reg;
                float v = acc[mi][ni][reg] + bv;
                if (EPI == 1) {
                    v += res[(long)row * N + col];
                    ((float*)Cw)[(long)row * N + col] = v;
                } else if (EPI == 2) {
                    v = 0.5f * v * (1.f + erff(v * 0.70710678118f));
                    ((u16*)Cw)[(long)row * N + col] = f2bf(v);
                } else {
                    ((u16*)Cw)[(long)row * N + col] = f2bf(v);
                }
            }
        }
    }
}

// ------- fc2 4-way split-K combine: out = P0+P1+P2+P3 + bias + res (partials bf16) ------
__global__ __launch_bounds__(192) void fc2_combine4(const u16* __restrict__ P0,
                                                    const u16* __restrict__ P1,
                                                    const u16* __restrict__ P2,
                                                    const u16* __restrict__ P3,
                                                    const float* __restrict__ bias,
                                                    const float* __restrict__ res,
                                                    float* __restrict__ out) {
    long row = blockIdx.x;
    int c = threadIdx.x * 4;
    long i = row * 768 + c;
    short4v a = *(const short4v*)(P0 + i);
    short4v b = *(const short4v*)(P1 + i);
    short4v d = *(const short4v*)(P2 + i);
    short4v e = *(const short4v*)(P3 + i);
    float4v bs = *(const float4v*)(bias + c);
    float4v rr = *(const float4v*)(res + i);
    float4v o;
    #pragma unroll
    for (int j = 0; j < 4; ++j)
        o[j] = (bf2f((u16)a[j]) + bf2f((u16)b[j])) + (bf2f((u16)d[j]) + bf2f((u16)e[j])) + bs[j] + rr[j];
    *(float4v*)(out + i) = o;
}

// ----- split-K flash attention (causal), swapped-QK^T + packed-P, chunk=512 -----
__device__ __constant__ u8 SLOT_QI[40] = {
    15,15,15,15, 14,14,14, 13,13,13, 12,12,12, 11,11,11, 10,10, 9,9, 8,8, 7,7, 6, 5, 4, 3,
    14,10,6,2,  13,9,5,1,  12,8,4,0 };
__device__ __constant__ u8 SLOT_C[40] = {
    0,1,2,3, 0,1,2, 0,1,2, 0,1,2, 0,1,2, 0,1, 0,1, 0,1, 0,1, 0, 0, 0, 0,
    3,2,1,0, 3,2,1,0, 3,2,1,0 };

__global__ __launch_bounds__(256) void attn_kernel(const u16* __restrict__ qkv,
                                                   const u16* __restrict__ Vt,
                                                   u16* __restrict__ Opart,
                                                   float* __restrict__ Ml) {
    __shared__ alignas(16) u16 Ks[2 * 64 * 64];
    __shared__ alignas(16) u16 Vs[2 * 64 * 64];
    __shared__ alignas(16) u16 Ps[4 * 16 * 64];
    int flat = blockIdx.x;
    int s = flat / 24, bh = flat % 24;
    int qi = SLOT_QI[s], c = SLOT_C[s];
    int b = bh / 12, h = bh % 12;
    int tid = threadIdx.x;
    int w = tid >> 6, lane = tid & 63;
    int g = lane >> 4, r = lane & 15;
    int qt0 = qi * 128;
    int qw0 = qt0 + w * 32;
    int kvbase = c * 512;
    int nit = (c < (qi >> 2)) ? 8 : (2 * (qi & 3) + 2);
    const u16* base = qkv + (long)b * 2048 * 2304;
    const u16* Qb = base + h * 64;
    const u16* Kb = base + 768 + h * 64;
    const u16* Vtb = Vt + (long)bh * 64 * 2048;

    const float SC = 0.125f * 1.44269504f;
    short8 qf[2][2];
    #pragma unroll
    for (int fi = 0; fi < 2; ++fi) {
        const u16* qrow = Qb + (long)(qw0 + fi * 16 + r) * 2304;
        qf[fi][0] = *(const short8*)(qrow + 8 * g);
        qf[fi][1] = *(const short8*)(qrow + 32 + 8 * g);
        #pragma unroll
        for (int kh = 0; kh < 2; ++kh)
            #pragma unroll
            for (int j = 0; j < 8; ++j)
                qf[fi][kh][j] = (short)f2bf(bf2f((u16)qf[fi][kh][j]) * SC);
    }

    f32x4 oacc[2][4] = {};
    float mrow[2] = {8.0f, 8.0f};
    float ps0[2] = {0.f, 0.f}, ps1[2] = {0.f, 0.f};

    auto stage = [&](int kt) {
        int kv0 = kvbase + kt * 64;
        u16* kb = Ks + (kt & 1) * 4096;
        u16* vb = Vs + (kt & 1) * 4096;
        #pragma unroll
        for (int j = 0; j < 2; ++j) {
            int cc = w * 128 + j * 64 + lane;
            int row = cc >> 3;
            int slot = (cc & 7) ^ (row & 7);
            gload_lds16(Kb + (long)(kv0 + row) * 2304 + slot * 8, kb + (w * 128 + j * 64) * 8);
            gload_lds16(Vtb + (long)row * 2048 + kv0 + slot * 8, vb + (w * 128 + j * 64) * 8);
        }
    };

    stage(0);
    for (int kt = 0; kt < nit; ++kt) {
        int kv0 = kvbase + kt * 64;
        if (kt + 1 < nit) {
            stage(kt + 1);
            asm volatile("s_waitcnt vmcnt(4)" ::: "memory");
        } else {
            asm volatile("s_waitcnt vmcnt(0)" ::: "memory");
        }
        __builtin_amdgcn_sched_barrier(0);
        __builtin_amdgcn_s_barrier();
        const u16* kb = Ks + (kt & 1) * 4096;
        const u16* vb = Vs + (kt & 1) * 4096;

        bool act0 = kv0 <= qw0 + 15;
        bool act1 = kv0 <= qw0 + 31;

        if (act1) {
            f32x4 sc[2][4] = {};
            __builtin_amdgcn_s_setprio(1);
            #pragma unroll
            for (int nt = 0; nt < 4; ++nt)
                #pragma unroll
                for (int kh = 0; kh < 2; ++kh) {
                    short8 bk = *(const short8*)(kb + (nt * 16 + r) * 64 + ((kh * 32 + g * 8) ^ ((r & 7) << 3)));
                    sc[1][nt] = __builtin_amdgcn_mfma_f32_16x16x32_bf16(bk, qf[1][kh], sc[1][nt], 0, 0, 0);
                    if (act0)
                        sc[0][nt] = __builtin_amdgcn_mfma_f32_16x16x32_bf16(bk, qf[0][kh], sc[0][nt], 0, 0, 0);
                }
            __builtin_amdgcn_s_setprio(0);

            #pragma unroll
            for (int fi = 0; fi < 2; ++fi) {
                if (fi == 0 && !act0) continue;
                if ((kv0 + 63) > (qw0 + fi * 16)) {
                    int q = qw0 + fi * 16 + r;
                    #pragma unroll
                    for (int nt = 0; nt < 4; ++nt)
                        #pragma unroll
                        for (int reg = 0; reg < 4; ++reg)
                            if ((kv0 + nt * 16 + g * 4 + reg) > q)
                                sc[fi][nt][reg] = -1e30f;
                }
            }

            float tl[2];
            bool need = false;
            #pragma unroll
            for (int fi = 0; fi < 2; ++fi) {
                if (fi == 0 && !act0) continue;
                float m0 = fmaxf(fmaxf(sc[fi][0][0], sc[fi][0][1]), fmaxf(sc[fi][0][2], sc[fi][0][3]));
                float m1 = fmaxf(fmaxf(sc[fi][1][0], sc[fi][1][1]), fmaxf(sc[fi][1][2], sc[fi][1][3]));
                float m2 = fmaxf(fmaxf(sc[fi][2][0], sc[fi][2][1]), fmaxf(sc[fi][2][2], sc[fi][2][3]));
                float m3 = fmaxf(fmaxf(sc[fi][3][0], sc[fi][3][1]), fmaxf(sc[fi][3][2], sc[fi][3][3]));
                tl[fi] = fmaxf(fmaxf(m0, m1), fmaxf(m2, m3));
                need = need || (tl[fi] > mrow[fi] + 8.f);
            }
            if (__any(need)) {
                #pragma unroll
                for (int fi = 0; fi < 2; ++fi) {
                    if (fi == 0 && !act0) continue;
                    float rm = tl[fi];
                    rm = fmaxf(rm, __shfl_xor(rm, 16));
                    rm = fmaxf(rm, __shfl_xor(rm, 32));
                    float mnew = fmaxf(mrow[fi], rm);
                    float alpha = exp2f(mrow[fi] - mnew);
                    mrow[fi] = mnew;
                    ps0[fi] *= alpha; ps1[fi] *= alpha;
                    #pragma unroll
                    for (int reg = 0; reg < 4; ++reg) {
                        float ar = __shfl(alpha, (lane & 48) | (g * 4 + reg));
                        #pragma unroll
                        for (int dt = 0; dt < 4; ++dt) oacc[fi][dt][reg] *= ar;
                    }
                }
            }

            u16* Pr = Ps + (w * 16 + r) * 64;
            short8 pf[2][2];
            #pragma unroll
            for (int fi = 0; fi < 2; ++fi) {
                if (fi == 0 && !act0) continue;
                #pragma unroll
                for (int nt = 0; nt < 4; ++nt) {
                    float p0 = exp2f(sc[fi][nt][0] - mrow[fi]);
                    float p1 = exp2f(sc[fi][nt][1] - mrow[fi]);
                    float p2 = exp2f(sc[fi][nt][2] - mrow[fi]);
                    float p3 = exp2f(sc[fi][nt][3] - mrow[fi]);
                    ps0[fi] += p0 + p2;
                    ps1[fi] += p1 + p3;
                    u32 lo = __builtin_amdgcn_perm(fbits(p1), fbits(p0), 0x07060302);
                    u32 hi = __builtin_amdgcn_perm(fbits(p3), fbits(p2), 0x07060302);
                    int col = (nt * 16 + g * 4) ^ ((r & 7) << 3);
                    *(u32x2*)(Pr + col) = u32x2{lo, hi};
                }
                pf[fi][0] = *(const short8*)(Pr + ((g * 8) ^ ((r & 7) << 3)));
                pf[fi][1] = *(const short8*)(Pr + ((32 + g * 8) ^ ((r & 7) << 3)));
            }

            __builtin_amdgcn_s_setprio(1);
            #pragma unroll
            for (int dt = 0; dt < 4; ++dt)
                #pragma unroll
                for (int kc = 0; kc < 2; ++kc) {
                    short8 vf = *(const short8*)(vb + (dt * 16 + r) * 64 + ((kc * 32 + g * 8) ^ ((r & 7) << 3)));
                    oacc[1][dt] = __builtin_amdgcn_mfma_f32_16x16x32_bf16(pf[1][kc], vf, oacc[1][dt], 0, 0, 0);
                    if (act0)
                        oacc[0][dt] = __builtin_amdgcn_mfma_f32_16x16x32_bf16(pf[0][kc], vf, oacc[0][dt], 0, 0, 0);
                }
            __builtin_amdgcn_s_setprio(0);
        }
        __builtin_amdgcn_s_barrier();
    }

    float lrow[2];
    #pragma unroll
    for (int fi = 0; fi < 2; ++fi) {
        float l = ps0[fi] + ps1[fi];
        l += __shfl_xor(l, 16);
        l += __shfl_xor(l, 32);
        lrow[fi] = l;
    }

    long pbase = ((long)c * 24 + bh) * 2048;
    #pragma unroll
    for (int fi = 0; fi < 2; ++fi)
        #pragma unroll
        for (int dt = 0; dt < 4; ++dt)
            #pragma unroll
            for (int reg = 0; reg < 4; ++reg) {
                int q = qw0 + fi * 16 + g * 4 + reg;
                int d = dt * 16 + r;
                Opart[(pbase + q) * 64 + d] = f2bf(oacc[fi][dt][reg]);
            }
    if ((lane & 48) == 0) {
        #pragma unroll
        for (int fi = 0; fi < 2; ++fi) {
            int q = qw0 + fi * 16 + r;
            Ml[(pbase + q) * 2]     = mrow[fi];
            Ml[(pbase + q) * 2 + 1] = lrow[fi];
        }
    }
}

// ---------------- combine split-K partials -> Ob bf16 [B*S][768] (d-pair vectorized) ------
__global__ __launch_bounds__(256) void attn_combine(const u16* __restrict__ Opart,
                                                    const float* __restrict__ Ml,
                                                    u16* __restrict__ Ob) {
    int bh = blockIdx.y;
    int b = bh / 12, h = bh % 12;
    int q = blockIdx.x * 8 + (threadIdx.x >> 5);
    int d = (threadIdx.x & 31) * 2;
    int qi = q >> 7;
    int nact = (qi >> 2) + 1;
    float mv[4], lv[4];
    float M = -1e30f;
    for (int c = 0; c < nact; ++c) {
        long base = ((long)c * 24 + bh) * 2048 + q;
        mv[c] = Ml[base * 2];
        lv[c] = Ml[base * 2 + 1];
        M = fmaxf(M, mv[c]);
    }
    float denom = 0.f, v0 = 0.f, v1 = 0.f;
    for (int c = 0; c < nact; ++c) {
        float wgt = exp2f(mv[c] - M);
        denom += lv[c] * wgt;
        u32 pr = *(const u32*)(Opart + ((((long)c * 24 + bh) * 2048 + q) * 64 + d));
        v0 += wgt * bf2f((u16)(pr & 0xffff));
        v1 += wgt * bf2f((u16)(pr >> 16));
    }
    float inv = 1.0f / denom;
    u32 o = (u32)f2bf(v0 * inv) | ((u32)f2bf(v1 * inv) << 16);
    *(u32*)(Ob + (((long)b * 2048 + q) * 768 + h * 64 + d)) = o;
}

extern "C" void kernel_launch(void* const* d_in, const int* in_sizes, int n_in,
                              void* d_out, int out_size, void* d_ws, size_t ws_size,
                              hipStream_t stream) {
    const float* x     = (const float*)d_in[0];
    const float* ln1_g = (const float*)d_in[1];
    const float* ln1_b = (const float*)d_in[2];
    const float* ln2_g = (const float*)d_in[3];
    const float* ln2_b = (const float*)d_in[4];
    const float* w_qkv = (const float*)d_in[5];
    const float* b_qkv = (const float*)d_in[6];
    const float* w_out = (const float*)d_in[7];
    const float* b_out = (const float*)d_in[8];
    const float* w_fc1 = (const float*)d_in[9];
    const float* b_fc1 = (const float*)d_in[10];
    const float* w_fc2 = (const float*)d_in[11];
    const float* b_fc2 = (const float*)d_in[12];

    char* ws = (char*)d_ws;
    size_t off = 0;
    auto alloc = [&](size_t bytes) { void* p = ws + off; off += (bytes + 255) & ~255ULL; return p; };
    u16* h1    = (u16*)alloc(4096UL * 768 * 2);    // dead after qkv GEMM
    u16* WqkvT = (u16*)alloc(2304UL * 768 * 2);    // dead after qkv GEMM
    u16* WoutT = (u16*)alloc(768UL * 768 * 2);
    u16* Wfc1T = (u16*)alloc(3072UL * 768 * 2);
    u16* Wfc2T = (u16*)alloc(768UL * 3072 * 2);
    u16* qkvb  = (u16*)alloc(4096UL * 2304 * 2);   // dead after attn
    u16* Vtb   = (u16*)alloc(24UL * 64 * 2048 * 2); // dead after attn
    u16* Ob    = (u16*)alloc(4096UL * 768 * 2);     // dead after out-proj
    float* x2  = (float*)alloc(4096UL * 768 * 4);
    // pool shared (time-disjoint): [h2 | gbuf] vs [Opart | Ml]
    char* pool = (char*)alloc(4096UL * 768 * 2 + 4096UL * 3072 * 2);
    u16* h2      = (u16*)pool;
    u16* gbuf    = (u16*)(pool + 4096UL * 768 * 2);
    u16* Opart   = (u16*)pool;
    float* Ml    = (float*)(pool + 4UL * 24 * 2048 * 64 * 2);
    // fc2 split-K (z=4) bf16 partials, aliased over buffers dead by fc2 time:
    u16* P0 = (u16*)qkvb;
    u16* P1 = (u16*)h1;
    u16* P2 = (u16*)Vtb;
    u16* P3 = (u16*)Ob;

    prep_kernel<<<dim3(11008), 256, 0, stream>>>(w_qkv, w_out, w_fc1, w_fc2,
                                                 WqkvT, WoutT, Wfc1T, Wfc2T,
                                                 x, ln1_g, ln1_b, h1);
    gemm_bf16<0><<<dim3(576, 1, 1), 256, 0, stream>>>(h1, 768, WqkvT, 768, b_qkv, nullptr, qkvb, nullptr, nullptr, nullptr, 4096, 2304, 768, 18);
    transpose_v<<<dim3(32, 24), 256, 0, stream>>>(qkvb, Vtb);
    attn_kernel<<<dim3(960), 256, 0, stream>>>(qkvb, Vtb, Opart, Ml);
    attn_combine<<<dim3(256, 24), 256, 0, stream>>>(Opart, Ml, Ob);
    gemm_bf16<1><<<dim3(192, 1, 1), 256, 0, stream>>>(Ob, 768, WoutT, 768, b_out, x, x2, nullptr, nullptr, nullptr, 4096, 768, 768, 6);
    ln_kernel<<<4096, 256, 0, stream>>>(x2, ln2_g, ln2_b, h2);
    gemm_bf16<2><<<dim3(768, 1, 1), 256, 0, stream>>>(h2, 768, Wfc1T, 768, b_fc1, nullptr, gbuf, nullptr, nullptr, nullptr, 4096, 3072, 768, 24);
    gemm_bf16<3><<<dim3(192, 1, 4), 256, 0, stream>>>(gbuf, 3072, Wfc2T, 3072, nullptr, nullptr, P0, P1, P2, P3, 4096, 768, 768, 6);
    fc2_combine4<<<4096, 192, 0, stream>>>(P0, P1, P2, P3, b_fc2, x2, (float*)d_out);
}

// Round 20
// 189.596 us; speedup vs baseline: 1.4843x; 1.0162x over previous
//
#include <hip/hip_runtime.h>
#include <hip/hip_bf16.h>

typedef unsigned short u16;
typedef unsigned int u32;
typedef unsigned char u8;
using short8 = __attribute__((ext_vector_type(8))) short;
using short4v = __attribute__((ext_vector_type(4))) short;
using f32x4  = __attribute__((ext_vector_type(4))) float;
using float4v = __attribute__((ext_vector_type(4))) float;
using u32x2  = __attribute__((ext_vector_type(2))) unsigned int;

__device__ __forceinline__ u16 f2bf(float f) {
    __hip_bfloat16 h = __float2bfloat16(f);
    union { __hip_bfloat16 h; u16 u; } cv; cv.h = h; return cv.u;
}
__device__ __forceinline__ float bf2f(u16 u) {
    union { u32 u; float f; } cv; cv.u = ((u32)u) << 16; return cv.f;
}
__device__ __forceinline__ u32 fbits(float f) {
    union { float f; u32 u; } cv; cv.f = f; return cv.u;
}

__device__ __forceinline__ void gload_lds16(const void* g, void* l) {
    __builtin_amdgcn_global_load_lds(
        (const __attribute__((address_space(1))) u32*)g,
        (__attribute__((address_space(3))) u32*)l, 16, 0, 0);
}

// bijective XCD-chunk remap (m204)
__device__ __forceinline__ int xcd_remap(int flat, int nwg) {
    int q = nwg >> 3, r = nwg & 7;
    int xcd = flat & 7, pos = flat >> 3;
    int start = xcd < r ? xcd * (q + 1) : r * (q + 1) + (xcd - r) * q;
    return start + pos;
}

// ---- prep: fused {4x weight transpose fp32->bf16} + {LayerNorm1} ----
__global__ __launch_bounds__(256) void prep_kernel(const float* __restrict__ Wq,
                                                   const float* __restrict__ Wo,
                                                   const float* __restrict__ Wf1,
                                                   const float* __restrict__ Wf2,
                                                   u16* __restrict__ Tq,
                                                   u16* __restrict__ To,
                                                   u16* __restrict__ Tf1,
                                                   u16* __restrict__ Tf2,
                                                   const float* __restrict__ x,
                                                   const float* __restrict__ gain,
                                                   const float* __restrict__ beta,
                                                   u16* __restrict__ h1) {
    __shared__ float tile[32][33];
    __shared__ float ws[8];
    int id = blockIdx.x;
    if (id < 6912) {
        const float* W; u16* Wt; int K, N, local;
        if (id < 1728)      { W = Wq;  Wt = Tq;  K = 768;  N = 2304; local = id; }
        else if (id < 2304) { W = Wo;  Wt = To;  K = 768;  N = 768;  local = id - 1728; }
        else if (id < 4608) { W = Wf1; Wt = Tf1; K = 768;  N = 3072; local = id - 2304; }
        else                { W = Wf2; Wt = Tf2; K = 3072; N = 768;  local = id - 4608; }
        int bx = N >> 5;
        int n0 = (local % bx) * 32, k0 = (local / bx) * 32;
        int tx = threadIdx.x & 31, ty = threadIdx.x >> 5;
        for (int i = 0; i < 4; i++) {
            int k = ty + i * 8;
            tile[k][tx] = W[(long)(k0 + k) * N + n0 + tx];
        }
        __syncthreads();
        for (int i = 0; i < 4; i++) {
            int n = ty + i * 8;
            Wt[(long)(n0 + n) * K + k0 + tx] = f2bf(tile[tx][n]);
        }
    } else {
        int row = id - 6912;
        const float* xr = x + (long)row * 768;
        int tid = threadIdx.x;
        float v[3];
        float s = 0.f, s2 = 0.f;
        for (int j = 0; j < 3; j++) {
            v[j] = xr[tid + 256 * j];
            s += v[j]; s2 += v[j] * v[j];
        }
        for (int off = 32; off; off >>= 1) {
            s  += __shfl_down(s, off);
            s2 += __shfl_down(s2, off);
        }
        int lane = tid & 63, w = tid >> 6;
        if (lane == 0) { ws[w] = s; ws[4 + w] = s2; }
        __syncthreads();
        s  = ws[0] + ws[1] + ws[2] + ws[3];
        s2 = ws[4] + ws[5] + ws[6] + ws[7];
        float mu  = s * (1.f / 768.f);
        float var = s2 * (1.f / 768.f) - mu * mu;
        float rs  = rsqrtf(var + 1e-5f);
        for (int j = 0; j < 3; j++) {
            int c = tid + 256 * j;
            h1[(long)row * 768 + c] = f2bf((v[j] - mu) * rs * gain[c] + beta[c]);
        }
    }
}

// ---------------- V transpose: qkv[B][S][2304] (V slice) -> Vt[B*H][64][2048] ------------
__global__ __launch_bounds__(256) void transpose_v(const u16* __restrict__ qkv,
                                                   u16* __restrict__ Vt) {
    __shared__ u16 tile[64][72];
    int s0 = blockIdx.x * 64;
    int bh = blockIdx.y;
    int b = bh / 12, h = bh % 12;
    int tid = threadIdx.x;
    const u16* src = qkv + (long)b * 2048 * 2304 + 1536 + h * 64;
    #pragma unroll
    for (int j = 0; j < 2; ++j) {
        int c = tid + j * 256;
        int srow = c >> 3, ch = c & 7;
        *(short8*)&tile[srow][ch * 8] = *(const short8*)(src + (long)(s0 + srow) * 2304 + ch * 8);
    }
    __syncthreads();
    u16* dst = Vt + (long)bh * 64 * 2048 + s0;
    #pragma unroll
    for (int j = 0; j < 2; ++j) {
        int c = tid + j * 256;
        int d = c >> 3, ch = c & 7;
        short8 v;
        #pragma unroll
        for (int e = 0; e < 8; ++e) v[e] = (short)tile[ch * 8 + e][d];
        *(short8*)(dst + (long)d * 2048 + ch * 8) = v;
    }
}

// ---------------- LayerNorm fp32 -> bf16 (standalone, for ln2) ----------------
__global__ __launch_bounds__(256) void ln_kernel(const float* __restrict__ x,
                                                 const float* __restrict__ gain,
                                                 const float* __restrict__ beta,
                                                 u16* __restrict__ out) {
    int row = blockIdx.x;
    const float* xr = x + (long)row * 768;
    int tid = threadIdx.x;
    float v[3];
    float s = 0.f, s2 = 0.f;
    for (int j = 0; j < 3; j++) {
        v[j] = xr[tid + 256 * j];
        s += v[j]; s2 += v[j] * v[j];
    }
    for (int off = 32; off; off >>= 1) {
        s  += __shfl_down(s, off);
        s2 += __shfl_down(s2, off);
    }
    __shared__ float ws[8];
    int lane = tid & 63, w = tid >> 6;
    if (lane == 0) { ws[w] = s; ws[4 + w] = s2; }
    __syncthreads();
    s  = ws[0] + ws[1] + ws[2] + ws[3];
    s2 = ws[4] + ws[5] + ws[6] + ws[7];
    float mu  = s * (1.f / 768.f);
    float var = s2 * (1.f / 768.f) - mu * mu;
    float rs  = rsqrtf(var + 1e-5f);
    for (int j = 0; j < 3; j++) {
        int c = tid + 256 * j;
        out[(long)row * 768 + c] = f2bf((v[j] - mu) * rs * gain[c] + beta[c]);
    }
}

// -- bf16 GEMM v7: MTx128 tile (MT=64/128), BK=32, 3-buffer ring, depth-2 counted vmcnt --
// EPI 0: bias->bf16; 1: bias+residual->fp32; 2: bias+gelu->bf16; 3: raw bf16 partial.
template <int EPI, int MT>
__global__ __launch_bounds__(256) void gemm_bf16(const u16* __restrict__ A, int lda,
                                                 const u16* __restrict__ Bt, int ldb,
                                                 const float* __restrict__ bias,
                                                 const float* __restrict__ res,
                                                 void* __restrict__ Cout0,
                                                 void* __restrict__ Cout1,
                                                 void* __restrict__ Cout2,
                                                 void* __restrict__ Cout3,
                                                 int M, int N, int K, int nN) {
    constexpr int MFRAG = MT / 32;          // A fragments per wave-row
    constexpr int INFLT = MT / 64 + 2;      // gload_lds per thread per stage
    __shared__ alignas(16) u16 As[3][MT * 32];
    __shared__ alignas(16) u16 Bs[3][128 * 32];
    int nwg = gridDim.x;
    int wgid = xcd_remap(blockIdx.x, nwg);
    int tN = (wgid % nN) * 128, tM = (wgid / nN) * MT;
    int z = blockIdx.z;
    const u16* Ab = A + (long)z * K;
    const u16* Bb = Bt + (long)z * K;
    void* Cw = (z == 0) ? Cout0 : (z == 1) ? Cout1 : (z == 2) ? Cout2 : Cout3;
    int tid = threadIdx.x;
    int wid = tid >> 6, lane = tid & 63;
    int wm = wid >> 1, wn = wid & 1;
    int g = lane >> 4, r = lane & 15;
    int srow = tid >> 2;
    int scol = tid & 3;

    f32x4 acc[MFRAG][4] = {};
    int KT = K >> 5;

    auto stage = [&](int kt, int buf) {
        int k0 = kt << 5;
        u16* ab = As[buf];
        u16* bb = Bs[buf];
        if constexpr (MT == 128) {
            #pragma unroll
            for (int j = 0; j < 2; ++j) {
                int row = j * 64 + srow;
                int slot = scol ^ (row & 3);
                gload_lds16(Ab + (long)(tM + row) * lda + k0 + slot * 8, ab + (j * 64 + wid * 16) * 32);
            }
        } else {
            int rowA = srow;
            int slotA = scol ^ (rowA & 3);
            gload_lds16(Ab + (long)(tM + rowA) * lda + k0 + slotA * 8, ab + tid * 8);
        }
        #pragma unroll
        for (int j = 0; j < 2; ++j) {
            int row = j * 64 + srow;
            int slot = scol ^ (row & 3);
            gload_lds16(Bb + (long)(tN + row) * ldb + k0 + slot * 8, bb + (j * 64 + wid * 16) * 32);
        }
    };

    stage(0, 0);
    stage(1, 1);
    int sb = 2, cb = 0;
    for (int kt = 0; kt < KT; ++kt) {
        if (kt + 2 < KT) {
            stage(kt + 2, sb);
            if (++sb == 3) sb = 0;
            asm volatile("s_waitcnt vmcnt(%0)" :: "i"(2 * INFLT) : "memory");
        } else if (kt + 1 < KT) {
            asm volatile("s_waitcnt vmcnt(%0)" :: "i"(INFLT) : "memory");
        } else {
            asm volatile("s_waitcnt vmcnt(0)" ::: "memory");
        }
        __builtin_amdgcn_sched_barrier(0);
        __builtin_amdgcn_s_barrier();
        const u16* ab = As[cb];
        const u16* bb = Bs[cb];
        if (++cb == 3) cb = 0;

        short8 af[MFRAG], bf[4];
        #pragma unroll
        for (int mi = 0; mi < MFRAG; ++mi) {
            int row = wm * (MT / 2) + mi * 16 + r;
            af[mi] = *(const short8*)(ab + row * 32 + ((g ^ (row & 3)) * 8));
        }
        #pragma unroll
        for (int ni = 0; ni < 4; ++ni) {
            int row = wn * 64 + ni * 16 + r;
            bf[ni] = *(const short8*)(bb + row * 32 + ((g ^ (row & 3)) * 8));
        }
        #pragma unroll
        for (int mi = 0; mi < MFRAG; ++mi)
            #pragma unroll
            for (int ni = 0; ni < 4; ++ni)
                acc[mi][ni] = __builtin_amdgcn_mfma_f32_16x16x32_bf16(af[mi], bf[ni], acc[mi][ni], 0, 0, 0);
        __builtin_amdgcn_s_barrier();
    }

    #pragma unroll
    for (int mi = 0; mi < MFRAG; mi++) {
        #pragma unroll
        for (int ni = 0; ni < 4; ni++) {
            int col = tN + wn * 64 + ni * 16 + r;
            float bv = (EPI == 3) ? 0.f : bias[col];
            #pragma unroll
            for (int reg = 0; reg < 4; reg++) {
                int row = tM + wm * (MT / 2) + mi * 16 + g * 4 + reg;
                float v = acc[mi][ni][reg] + bv;
                if (EPI == 1) {
                    v += res[(long)row * N + col];
                    ((float*)Cw)[(long)row * N + col] = v;
                } else if (EPI == 2) {
                    v = 0.5f * v * (1.f + erff(v * 0.70710678118f));
                    ((u16*)Cw)[(long)row * N + col] = f2bf(v);
                } else {
                    ((u16*)Cw)[(long)row * N + col] = f2bf(v);
                }
            }
        }
    }
}

// ------- fc2 4-way split-K combine: out = P0+P1+P2+P3 + bias + res (partials bf16) ------
__global__ __launch_bounds__(192) void fc2_combine4(const u16* __restrict__ P0,
                                                    const u16* __restrict__ P1,
                                                    const u16* __restrict__ P2,
                                                    const u16* __restrict__ P3,
                                                    const float* __restrict__ bias,
                                                    const float* __restrict__ res,
                                                    float* __restrict__ out) {
    long row = blockIdx.x;
    int c = threadIdx.x * 4;
    long i = row * 768 + c;
    short4v a = *(const short4v*)(P0 + i);
    short4v b = *(const short4v*)(P1 + i);
    short4v d = *(const short4v*)(P2 + i);
    short4v e = *(const short4v*)(P3 + i);
    float4v bs = *(const float4v*)(bias + c);
    float4v rr = *(const float4v*)(res + i);
    float4v o;
    #pragma unroll
    for (int j = 0; j < 4; ++j)
        o[j] = (bf2f((u16)a[j]) + bf2f((u16)b[j])) + (bf2f((u16)d[j]) + bf2f((u16)e[j])) + bs[j] + rr[j];
    *(float4v*)(out + i) = o;
}

// ----- split-K flash attention (causal), swapped-QK^T + packed-P, chunk=512 -----
__device__ __constant__ u8 SLOT_QI[40] = {
    15,15,15,15, 14,14,14, 13,13,13, 12,12,12, 11,11,11, 10,10, 9,9, 8,8, 7,7, 6, 5, 4, 3,
    14,10,6,2,  13,9,5,1,  12,8,4,0 };
__device__ __constant__ u8 SLOT_C[40] = {
    0,1,2,3, 0,1,2, 0,1,2, 0,1,2, 0,1,2, 0,1, 0,1, 0,1, 0,1, 0, 0, 0, 0,
    3,2,1,0, 3,2,1,0, 3,2,1,0 };

__global__ __launch_bounds__(256) void attn_kernel(const u16* __restrict__ qkv,
                                                   const u16* __restrict__ Vt,
                                                   u16* __restrict__ Opart,
                                                   float* __restrict__ Ml) {
    __shared__ alignas(16) u16 Ks[2 * 64 * 64];
    __shared__ alignas(16) u16 Vs[2 * 64 * 64];
    __shared__ alignas(16) u16 Ps[4 * 16 * 64];
    int flat = blockIdx.x;
    int s = flat / 24, bh = flat % 24;
    int qi = SLOT_QI[s], c = SLOT_C[s];
    int b = bh / 12, h = bh % 12;
    int tid = threadIdx.x;
    int w = tid >> 6, lane = tid & 63;
    int g = lane >> 4, r = lane & 15;
    int qt0 = qi * 128;
    int qw0 = qt0 + w * 32;
    int kvbase = c * 512;
    int nit = (c < (qi >> 2)) ? 8 : (2 * (qi & 3) + 2);
    const u16* base = qkv + (long)b * 2048 * 2304;
    const u16* Qb = base + h * 64;
    const u16* Kb = base + 768 + h * 64;
    const u16* Vtb = Vt + (long)bh * 64 * 2048;

    const float SC = 0.125f * 1.44269504f;
    short8 qf[2][2];
    #pragma unroll
    for (int fi = 0; fi < 2; ++fi) {
        const u16* qrow = Qb + (long)(qw0 + fi * 16 + r) * 2304;
        qf[fi][0] = *(const short8*)(qrow + 8 * g);
        qf[fi][1] = *(const short8*)(qrow + 32 + 8 * g);
        #pragma unroll
        for (int kh = 0; kh < 2; ++kh)
            #pragma unroll
            for (int j = 0; j < 8; ++j)
                qf[fi][kh][j] = (short)f2bf(bf2f((u16)qf[fi][kh][j]) * SC);
    }

    f32x4 oacc[2][4] = {};
    float mrow[2] = {8.0f, 8.0f};
    float ps0[2] = {0.f, 0.f}, ps1[2] = {0.f, 0.f};

    auto stage = [&](int kt) {
        int kv0 = kvbase + kt * 64;
        u16* kb = Ks + (kt & 1) * 4096;
        u16* vb = Vs + (kt & 1) * 4096;
        #pragma unroll
        for (int j = 0; j < 2; ++j) {
            int cc = w * 128 + j * 64 + lane;
            int row = cc >> 3;
            int slot = (cc & 7) ^ (row & 7);
            gload_lds16(Kb + (long)(kv0 + row) * 2304 + slot * 8, kb + (w * 128 + j * 64) * 8);
            gload_lds16(Vtb + (long)row * 2048 + kv0 + slot * 8, vb + (w * 128 + j * 64) * 8);
        }
    };

    stage(0);
    for (int kt = 0; kt < nit; ++kt) {
        int kv0 = kvbase + kt * 64;
        if (kt + 1 < nit) {
            stage(kt + 1);
            asm volatile("s_waitcnt vmcnt(4)" ::: "memory");
        } else {
            asm volatile("s_waitcnt vmcnt(0)" ::: "memory");
        }
        __builtin_amdgcn_sched_barrier(0);
        __builtin_amdgcn_s_barrier();
        const u16* kb = Ks + (kt & 1) * 4096;
        const u16* vb = Vs + (kt & 1) * 4096;

        bool act0 = kv0 <= qw0 + 15;
        bool act1 = kv0 <= qw0 + 31;

        if (act1) {
            f32x4 sc[2][4] = {};
            __builtin_amdgcn_s_setprio(1);
            #pragma unroll
            for (int nt = 0; nt < 4; ++nt)
                #pragma unroll
                for (int kh = 0; kh < 2; ++kh) {
                    short8 bk = *(const short8*)(kb + (nt * 16 + r) * 64 + ((kh * 32 + g * 8) ^ ((r & 7) << 3)));
                    sc[1][nt] = __builtin_amdgcn_mfma_f32_16x16x32_bf16(bk, qf[1][kh], sc[1][nt], 0, 0, 0);
                    if (act0)
                        sc[0][nt] = __builtin_amdgcn_mfma_f32_16x16x32_bf16(bk, qf[0][kh], sc[0][nt], 0, 0, 0);
                }
            __builtin_amdgcn_s_setprio(0);

            #pragma unroll
            for (int fi = 0; fi < 2; ++fi) {
                if (fi == 0 && !act0) continue;
                if ((kv0 + 63) > (qw0 + fi * 16)) {
                    int q = qw0 + fi * 16 + r;
                    #pragma unroll
                    for (int nt = 0; nt < 4; ++nt)
                        #pragma unroll
                        for (int reg = 0; reg < 4; ++reg)
                            if ((kv0 + nt * 16 + g * 4 + reg) > q)
                                sc[fi][nt][reg] = -1e30f;
                }
            }

            float tl[2];
            bool need = false;
            #pragma unroll
            for (int fi = 0; fi < 2; ++fi) {
                if (fi == 0 && !act0) continue;
                float m0 = fmaxf(fmaxf(sc[fi][0][0], sc[fi][0][1]), fmaxf(sc[fi][0][2], sc[fi][0][3]));
                float m1 = fmaxf(fmaxf(sc[fi][1][0], sc[fi][1][1]), fmaxf(sc[fi][1][2], sc[fi][1][3]));
                float m2 = fmaxf(fmaxf(sc[fi][2][0], sc[fi][2][1]), fmaxf(sc[fi][2][2], sc[fi][2][3]));
                float m3 = fmaxf(fmaxf(sc[fi][3][0], sc[fi][3][1]), fmaxf(sc[fi][3][2], sc[fi][3][3]));
                tl[fi] = fmaxf(fmaxf(m0, m1), fmaxf(m2, m3));
                need = need || (tl[fi] > mrow[fi] + 8.f);
            }
            if (__any(need)) {
                #pragma unroll
                for (int fi = 0; fi < 2; ++fi) {
                    if (fi == 0 && !act0) continue;
                    float rm = tl[fi];
                    rm = fmaxf(rm, __shfl_xor(rm, 16));
                    rm = fmaxf(rm, __shfl_xor(rm, 32));
                    float mnew = fmaxf(mrow[fi], rm);
                    float alpha = exp2f(mrow[fi] - mnew);
                    mrow[fi] = mnew;
                    ps0[fi] *= alpha; ps1[fi] *= alpha;
                    #pragma unroll
                    for (int reg = 0; reg < 4; ++reg) {
                        float ar = __shfl(alpha, (lane & 48) | (g * 4 + reg));
                        #pragma unroll
                        for (int dt = 0; dt < 4; ++dt) oacc[fi][dt][reg] *= ar;
                    }
                }
            }

            u16* Pr = Ps + (w * 16 + r) * 64;
            short8 pf[2][2];
            #pragma unroll
            for (int fi = 0; fi < 2; ++fi) {
                if (fi == 0 && !act0) continue;
                #pragma unroll
                for (int nt = 0; nt < 4; ++nt) {
                    float p0 = exp2f(sc[fi][nt][0] - mrow[fi]);
                    float p1 = exp2f(sc[fi][nt][1] - mrow[fi]);
                    float p2 = exp2f(sc[fi][nt][2] - mrow[fi]);
                    float p3 = exp2f(sc[fi][nt][3] - mrow[fi]);
                    ps0[fi] += p0 + p2;
                    ps1[fi] += p1 + p3;
                    u32 lo = __builtin_amdgcn_perm(fbits(p1), fbits(p0), 0x07060302);
                    u32 hi = __builtin_amdgcn_perm(fbits(p3), fbits(p2), 0x07060302);
                    int col = (nt * 16 + g * 4) ^ ((r & 7) << 3);
                    *(u32x2*)(Pr + col) = u32x2{lo, hi};
                }
                pf[fi][0] = *(const short8*)(Pr + ((g * 8) ^ ((r & 7) << 3)));
                pf[fi][1] = *(const short8*)(Pr + ((32 + g * 8) ^ ((r & 7) << 3)));
            }

            __builtin_amdgcn_s_setprio(1);
            #pragma unroll
            for (int dt = 0; dt < 4; ++dt)
                #pragma unroll
                for (int kc = 0; kc < 2; ++kc) {
                    short8 vf = *(const short8*)(vb + (dt * 16 + r) * 64 + ((kc * 32 + g * 8) ^ ((r & 7) << 3)));
                    oacc[1][dt] = __builtin_amdgcn_mfma_f32_16x16x32_bf16(pf[1][kc], vf, oacc[1][dt], 0, 0, 0);
                    if (act0)
                        oacc[0][dt] = __builtin_amdgcn_mfma_f32_16x16x32_bf16(pf[0][kc], vf, oacc[0][dt], 0, 0, 0);
                }
            __builtin_amdgcn_s_setprio(0);
        }
        __builtin_amdgcn_s_barrier();
    }

    float lrow[2];
    #pragma unroll
    for (int fi = 0; fi < 2; ++fi) {
        float l = ps0[fi] + ps1[fi];
        l += __shfl_xor(l, 16);
        l += __shfl_xor(l, 32);
        lrow[fi] = l;
    }

    long pbase = ((long)c * 24 + bh) * 2048;
    #pragma unroll
    for (int fi = 0; fi < 2; ++fi)
        #pragma unroll
        for (int dt = 0; dt < 4; ++dt)
            #pragma unroll
            for (int reg = 0; reg < 4; ++reg) {
                int q = qw0 + fi * 16 + g * 4 + reg;
                int d = dt * 16 + r;
                Opart[(pbase + q) * 64 + d] = f2bf(oacc[fi][dt][reg]);
            }
    if ((lane & 48) == 0) {
        #pragma unroll
        for (int fi = 0; fi < 2; ++fi) {
            int q = qw0 + fi * 16 + r;
            Ml[(pbase + q) * 2]     = mrow[fi];
            Ml[(pbase + q) * 2 + 1] = lrow[fi];
        }
    }
}

// ---------------- combine split-K partials -> Ob bf16 [B*S][768] (d-pair vectorized) ------
__global__ __launch_bounds__(256) void attn_combine(const u16* __restrict__ Opart,
                                                    const float* __restrict__ Ml,
                                                    u16* __restrict__ Ob) {
    int bh = blockIdx.y;
    int b = bh / 12, h = bh % 12;
    int q = blockIdx.x * 8 + (threadIdx.x >> 5);
    int d = (threadIdx.x & 31) * 2;
    int qi = q >> 7;
    int nact = (qi >> 2) + 1;
    float mv[4], lv[4];
    float M = -1e30f;
    for (int c = 0; c < nact; ++c) {
        long base = ((long)c * 24 + bh) * 2048 + q;
        mv[c] = Ml[base * 2];
        lv[c] = Ml[base * 2 + 1];
        M = fmaxf(M, mv[c]);
    }
    float denom = 0.f, v0 = 0.f, v1 = 0.f;
    for (int c = 0; c < nact; ++c) {
        float wgt = exp2f(mv[c] - M);
        denom += lv[c] * wgt;
        u32 pr = *(const u32*)(Opart + ((((long)c * 24 + bh) * 2048 + q) * 64 + d));
        v0 += wgt * bf2f((u16)(pr & 0xffff));
        v1 += wgt * bf2f((u16)(pr >> 16));
    }
    float inv = 1.0f / denom;
    u32 o = (u32)f2bf(v0 * inv) | ((u32)f2bf(v1 * inv) << 16);
    *(u32*)(Ob + (((long)b * 2048 + q) * 768 + h * 64 + d)) = o;
}

extern "C" void kernel_launch(void* const* d_in, const int* in_sizes, int n_in,
                              void* d_out, int out_size, void* d_ws, size_t ws_size,
                              hipStream_t stream) {
    const float* x     = (const float*)d_in[0];
    const float* ln1_g = (const float*)d_in[1];
    const float* ln1_b = (const float*)d_in[2];
    const float* ln2_g = (const float*)d_in[3];
    const float* ln2_b = (const float*)d_in[4];
    const float* w_qkv = (const float*)d_in[5];
    const float* b_qkv = (const float*)d_in[6];
    const float* w_out = (const float*)d_in[7];
    const float* b_out = (const float*)d_in[8];
    const float* w_fc1 = (const float*)d_in[9];
    const float* b_fc1 = (const float*)d_in[10];
    const float* w_fc2 = (const float*)d_in[11];
    const float* b_fc2 = (const float*)d_in[12];

    char* ws = (char*)d_ws;
    size_t off = 0;
    auto alloc = [&](size_t bytes) { void* p = ws + off; off += (bytes + 255) & ~255ULL; return p; };
    u16* h1    = (u16*)alloc(4096UL * 768 * 2);    // dead after qkv GEMM
    u16* WqkvT = (u16*)alloc(2304UL * 768 * 2);    // dead after qkv GEMM
    u16* WoutT = (u16*)alloc(768UL * 768 * 2);
    u16* Wfc1T = (u16*)alloc(3072UL * 768 * 2);
    u16* Wfc2T = (u16*)alloc(768UL * 3072 * 2);
    u16* qkvb  = (u16*)alloc(4096UL * 2304 * 2);   // dead after attn
    u16* Vtb   = (u16*)alloc(24UL * 64 * 2048 * 2); // dead after attn
    u16* Ob    = (u16*)alloc(4096UL * 768 * 2);     // dead after out-proj
    float* x2  = (float*)alloc(4096UL * 768 * 4);
    // pool shared (time-disjoint): [h2 | gbuf] vs [Opart | Ml]
    char* pool = (char*)alloc(4096UL * 768 * 2 + 4096UL * 3072 * 2);
    u16* h2      = (u16*)pool;
    u16* gbuf    = (u16*)(pool + 4096UL * 768 * 2);
    u16* Opart   = (u16*)pool;
    float* Ml    = (float*)(pool + 4UL * 24 * 2048 * 64 * 2);
    // fc2 split-K (z=4) bf16 partials, aliased over buffers dead by fc2 time:
    u16* P0 = (u16*)qkvb;
    u16* P1 = (u16*)h1;
    u16* P2 = (u16*)Vtb;
    u16* P3 = (u16*)Ob;

    prep_kernel<<<dim3(11008), 256, 0, stream>>>(w_qkv, w_out, w_fc1, w_fc2,
                                                 WqkvT, WoutT, Wfc1T, Wfc2T,
                                                 x, ln1_g, ln1_b, h1);
    gemm_bf16<0, 128><<<dim3(576, 1, 1), 256, 0, stream>>>(h1, 768, WqkvT, 768, b_qkv, nullptr, qkvb, nullptr, nullptr, nullptr, 4096, 2304, 768, 18);
    transpose_v<<<dim3(32, 24), 256, 0, stream>>>(qkvb, Vtb);
    attn_kernel<<<dim3(960), 256, 0, stream>>>(qkvb, Vtb, Opart, Ml);
    attn_combine<<<dim3(256, 24), 256, 0, stream>>>(Opart, Ml, Ob);
    gemm_bf16<1, 64><<<dim3(384, 1, 1), 256, 0, stream>>>(Ob, 768, WoutT, 768, b_out, x, x2, nullptr, nullptr, nullptr, 4096, 768, 768, 6);
    ln_kernel<<<4096, 256, 0, stream>>>(x2, ln2_g, ln2_b, h2);
    gemm_bf16<2, 128><<<dim3(768, 1, 1), 256, 0, stream>>>(h2, 768, Wfc1T, 768, b_fc1, nullptr, gbuf, nullptr, nullptr, nullptr, 4096, 3072, 768, 24);
    gemm_bf16<3, 128><<<dim3(192, 1, 4), 256, 0, stream>>>(gbuf, 3072, Wfc2T, 3072, nullptr, nullptr, P0, P1, P2, P3, 4096, 768, 768, 6);
    fc2_combine4<<<4096, 192, 0, stream>>>(P0, P1, P2, P3, b_fc2, x2, (float*)d_out);
}